// Round 1
// baseline (232.177 us; speedup 1.0000x reference)
//
#include <hip/hip_runtime.h>

#define NB 128
#define NL 2048
#define NH 256
#define CHUNK 32
#define NCHUNK (NL / CHUNK)   // 64
#define WORDS (CHUNK * 3)     // 96 floats of x per chunk

__device__ __forceinline__ float fexp2(float v) { return __builtin_amdgcn_exp2f(v); }
__device__ __forceinline__ float frcp(float v)  { return __builtin_amdgcn_rcpf(v); }

// ---------------------------------------------------------------------------
// Fold the K=3 projection through the recurrent weight matrices:
//   Mz = Wp@Wz (3x256), cz = bp@Wz + bz   (same for h with Wh,bh)
// Layout in ws: per channel j, 8 floats: [Mz0,Mz1,Mz2,cz, Mh0,Mh1,Mh2,ch]
// ---------------------------------------------------------------------------
__global__ void fold_kernel(const float* __restrict__ Wp, const float* __restrict__ bp,
                            const float* __restrict__ Wz, const float* __restrict__ bz,
                            const float* __restrict__ Wh, const float* __restrict__ bh,
                            float* __restrict__ wsW) {
    const int j = blockIdx.x * 64 + threadIdx.x;   // 0..255, grid <<<4,64>>>
    float mz0 = 0.f, mz1 = 0.f, mz2 = 0.f, cz = 0.f;
    float mh0 = 0.f, mh1 = 0.f, mh2 = 0.f, ch = 0.f;
#pragma unroll 8
    for (int h = 0; h < NH; ++h) {
        const float wz = Wz[h * NH + j];   // coalesced across j
        const float wh = Wh[h * NH + j];
        const float p0 = Wp[h];            // broadcast
        const float p1 = Wp[NH + h];
        const float p2 = Wp[2 * NH + h];
        const float bb = bp[h];
        mz0 = fmaf(p0, wz, mz0); mz1 = fmaf(p1, wz, mz1); mz2 = fmaf(p2, wz, mz2);
        cz  = fmaf(bb, wz, cz);
        mh0 = fmaf(p0, wh, mh0); mh1 = fmaf(p1, wh, mh1); mh2 = fmaf(p2, wh, mh2);
        ch  = fmaf(bb, wh, ch);
    }
    cz += bz[j];
    ch += bh[j];
    float4* w4 = (float4*)(wsW + j * 8);
    w4[0] = make_float4(mz0, mz1, mz2, cz);
    w4[1] = make_float4(mh0, mh1, mh2, ch);
}

// ---------------------------------------------------------------------------
// Path A scan: 512 blocks x 64 threads. Block = (batch b, channel-group g).
// Lane owns one channel. Writes per-group partial pred streams to ws.
// ---------------------------------------------------------------------------
__global__ __launch_bounds__(64) void scan_kernel_ws(
        const float* __restrict__ x, const float* __restrict__ wsW,
        const float* __restrict__ Wg, float* __restrict__ part) {
    const int lane = threadIdx.x;
    const int b = blockIdx.x >> 2;
    const int g = blockIdx.x & 3;
    const int chn = g * 64 + lane;

    const float4* wv = (const float4*)(wsW + chn * 8);
    const float4 wA = wv[0];                 // Mz0,Mz1,Mz2,cz
    const float4 wB = wv[1];                 // Mh0,Mh1,Mh2,ch
    const float  wg = Wg[chn];

    const float* xb = x + (size_t)b * (NL * 3);
    float* pout = part + (size_t)(g * NB + b) * NL;

    __shared__ float4 xbuf[2][CHUNK];        // x padded to 4 floats per t
    float* xbf = (float*)xbuf;

    // staging word assignment: lane loads word lane (and 64+lane if lane<32)
    const int w0 = lane;
    const int w1 = 64 + lane;
    const int s0 = (w0 / 3) * 4 + (w0 % 3);
    const int s1 = (w1 / 3) * 4 + (w1 % 3);

    // prologue: stage chunk 0
    {
        float v0 = xb[w0];
        float v1 = (lane < 32) ? xb[w1] : 0.f;
        xbf[s0] = v0;
        if (lane < 32) xbf[s1] = v1;
    }

    float h = 0.f;
    for (int c = 0; c < NCHUNK; ++c) {
        const int cur = c & 1;
        // issue next-chunk x loads early (latency hidden under scan compute)
        float nv0 = 0.f, nv1 = 0.f;
        if (c + 1 < NCHUNK) {
            const float* xn = xb + (c + 1) * WORDS;
            nv0 = xn[w0];
            if (lane < 32) nv1 = xn[w1];
        }

        float p[CHUNK];
        const float4* xc = xbuf[cur];
#pragma unroll
        for (int t = 0; t < CHUNK; ++t) {
            const float4 xv = xc[t];         // LDS broadcast (all lanes same addr)
            const float vz = fmaf(xv.x, wA.x, fmaf(xv.y, wA.y, fmaf(xv.z, wA.z, wA.w)));
            const float vh = fmaf(xv.x, wB.x, fmaf(xv.y, wB.y, fmaf(xv.z, wB.z, wB.w)));
            const float z  = frcp(1.0f + fexp2(vz * -1.4426950408889634f)); // sigmoid
            const float sg = frcp(1.0f + fexp2(vh * -2.8853900817779268f)); // sigmoid(2v)
            const float ht = fmaf(2.0f, sg, -1.0f);                          // tanh(v)
            p[t] = h * wg;                   // pred uses h BEFORE update
            h = fmaf(z, ht - h, h);          // h = (1-z)h + z*ht
        }

        // butterfly-reduce each p[t] across the 64 lanes (batched for ILP)
#pragma unroll
        for (int t = 0; t < CHUNK; ++t) {
            float v = p[t];
            v += __shfl_xor(v, 1, 64);
            v += __shfl_xor(v, 2, 64);
            v += __shfl_xor(v, 4, 64);
            v += __shfl_xor(v, 8, 64);
            v += __shfl_xor(v, 16, 64);
            v += __shfl_xor(v, 32, 64);
            p[t] = v;
        }
        if (lane == 0) {
            float4* dst = (float4*)(pout + c * CHUNK);
#pragma unroll
            for (int j2 = 0; j2 < CHUNK / 4; ++j2)
                dst[j2] = make_float4(p[4*j2], p[4*j2+1], p[4*j2+2], p[4*j2+3]);
        }
        // write staged x into the other buffer (single wave: no barrier needed)
        if (c + 1 < NCHUNK) {
            float* nb2 = xbf + (cur ^ 1) * CHUNK * 4;
            nb2[s0] = nv0;
            if (lane < 32) nb2[s1] = nv1;
        }
    }
}

__global__ void combine_kernel(const float* __restrict__ part,
                               const float* __restrict__ bg,
                               float* __restrict__ out) {
    const int i = blockIdx.x * 256 + threadIdx.x;
    out[i] = part[i] + part[i + NB * NL] + part[i + 2 * NB * NL]
           + part[i + 3 * NB * NL] + bg[0];
}

// ---------------------------------------------------------------------------
// Path B scan (fallback if ws too small for partials): 128 blocks x 256 thr.
// 4 waves per block (one channel-group each), cross-wave pred combine in LDS.
// ---------------------------------------------------------------------------
__global__ __launch_bounds__(256) void scan_kernel_nows(
        const float* __restrict__ x, const float* __restrict__ wsW,
        const float* __restrict__ Wg, const float* __restrict__ bg,
        float* __restrict__ out) {
    const int tid  = threadIdx.x;
    const int lane = tid & 63;
    const int wid  = tid >> 6;               // channel group
    const int b = blockIdx.x;
    const int chn = wid * 64 + lane;

    const float4* wv = (const float4*)(wsW + chn * 8);
    const float4 wA = wv[0];
    const float4 wB = wv[1];
    const float  wg = Wg[chn];
    const float  bgv = bg[0];

    const float* xb = x + (size_t)b * (NL * 3);

    __shared__ float4 xbuf[2][CHUNK];
    __shared__ float  predbuf[2][4][CHUNK];
    float* xbf = (float*)xbuf;

    const int sw = tid;                      // staging word (tid<96)
    const int sidx = (sw / 3) * 4 + (sw % 3);

    if (tid < WORDS) xbf[sidx] = xb[sw];
    __syncthreads();

    float h = 0.f;
    for (int c = 0; c < NCHUNK; ++c) {
        const int cur = c & 1;
        float nv = 0.f;
        if (tid < WORDS && c + 1 < NCHUNK) nv = xb[(c + 1) * WORDS + sw];

        float p[CHUNK];
        const float4* xc = xbuf[cur];
#pragma unroll
        for (int t = 0; t < CHUNK; ++t) {
            const float4 xv = xc[t];
            const float vz = fmaf(xv.x, wA.x, fmaf(xv.y, wA.y, fmaf(xv.z, wA.z, wA.w)));
            const float vh = fmaf(xv.x, wB.x, fmaf(xv.y, wB.y, fmaf(xv.z, wB.z, wB.w)));
            const float z  = frcp(1.0f + fexp2(vz * -1.4426950408889634f));
            const float sg = frcp(1.0f + fexp2(vh * -2.8853900817779268f));
            const float ht = fmaf(2.0f, sg, -1.0f);
            p[t] = h * wg;
            h = fmaf(z, ht - h, h);
        }
#pragma unroll
        for (int t = 0; t < CHUNK; ++t) {
            float v = p[t];
            v += __shfl_xor(v, 1, 64);
            v += __shfl_xor(v, 2, 64);
            v += __shfl_xor(v, 4, 64);
            v += __shfl_xor(v, 8, 64);
            v += __shfl_xor(v, 16, 64);
            v += __shfl_xor(v, 32, 64);
            p[t] = v;
        }
        if (lane == 0) {
            float4* dpr = (float4*)&predbuf[cur][wid][0];
#pragma unroll
            for (int j2 = 0; j2 < CHUNK / 4; ++j2)
                dpr[j2] = make_float4(p[4*j2], p[4*j2+1], p[4*j2+2], p[4*j2+3]);
        }
        if (tid < WORDS && c + 1 < NCHUNK) xbf[(cur ^ 1) * CHUNK * 4 + sidx] = nv;
        __syncthreads();
        if (tid < CHUNK) {
            const float s = predbuf[cur][0][tid] + predbuf[cur][1][tid]
                          + predbuf[cur][2][tid] + predbuf[cur][3][tid];
            out[(size_t)b * NL + c * CHUNK + tid] = s + bgv;
        }
        // predbuf/xbuf are double-buffered: next chunk's writes hit the other
        // slot, and the c+2 reuse is fenced by the c+1 barrier. No 2nd barrier.
    }
}

extern "C" void kernel_launch(void* const* d_in, const int* in_sizes, int n_in,
                              void* d_out, int out_size, void* d_ws, size_t ws_size,
                              hipStream_t stream) {
    const float* x  = (const float*)d_in[0];
    const float* Wp = (const float*)d_in[1];
    const float* bp = (const float*)d_in[2];
    const float* Wz = (const float*)d_in[3];
    const float* bz = (const float*)d_in[4];
    const float* Wh = (const float*)d_in[5];
    const float* bh = (const float*)d_in[6];
    const float* Wg = (const float*)d_in[7];
    const float* bg = (const float*)d_in[8];
    float* out = (float*)d_out;

    float* wsW  = (float*)d_ws;              // 8KB folded weights
    float* part = wsW + 8 * NH;              // 4MB partial pred streams

    fold_kernel<<<4, 64, 0, stream>>>(Wp, bp, Wz, bz, Wh, bh, wsW);

    const size_t need = (size_t)(8 * NH) * sizeof(float)
                      + (size_t)4 * NB * NL * sizeof(float);
    if (ws_size >= need) {
        scan_kernel_ws<<<NB * 4, 64, 0, stream>>>(x, wsW, Wg, part);
        combine_kernel<<<(NB * NL) / 256, 256, 0, stream>>>(part, bg, out);
    } else {
        scan_kernel_nows<<<NB, 256, 0, stream>>>(x, wsW, Wg, bg, out);
    }
}

// Round 2
// 96.986 us; speedup vs baseline: 2.3939x; 2.3939x over previous
//
#include <hip/hip_runtime.h>

#define NB 128
#define NL 2048
#define NH 256
#define NSEG 16
#define SEGLEN (NL / NSEG)   // 128
#define RCHUNK 16            // pred-reduce chunk inside pass3
#define CHUNK 32             // fallback kernel chunking
#define NCHUNK (NL / CHUNK)
#define WORDS (CHUNK * 3)

__device__ __forceinline__ float fexp2(float v) { return __builtin_amdgcn_exp2f(v); }
__device__ __forceinline__ float frcp(float v)  { return __builtin_amdgcn_rcpf(v); }

// ---------------------------------------------------------------------------
// Fold K=3 projection through Wz/Wh, AND pre-scale by the exp2 constants:
//   A-side (update gate z):  arg1 = -log2(e) * (x·Mz + cz)   -> z = 1/(1+2^arg1)
//   B-side (candidate tanh): arg2 = -2log2(e) * (x·Mh + ch)  -> tanh = 2/(1+2^arg2)-1
// Layout per channel j: 8 floats [Mz0,Mz1,Mz2,cz, Mh0,Mh1,Mh2,ch] (pre-scaled)
// ---------------------------------------------------------------------------
__global__ void fold_kernel(const float* __restrict__ Wp, const float* __restrict__ bp,
                            const float* __restrict__ Wz, const float* __restrict__ bz,
                            const float* __restrict__ Wh, const float* __restrict__ bh,
                            float* __restrict__ wsW) {
    const int j = blockIdx.x * 64 + threadIdx.x;   // grid <<<4,64>>>
    float mz0 = 0.f, mz1 = 0.f, mz2 = 0.f, cz = 0.f;
    float mh0 = 0.f, mh1 = 0.f, mh2 = 0.f, ch = 0.f;
#pragma unroll 8
    for (int h = 0; h < NH; ++h) {
        const float wz = Wz[h * NH + j];
        const float wh = Wh[h * NH + j];
        const float p0 = Wp[h];
        const float p1 = Wp[NH + h];
        const float p2 = Wp[2 * NH + h];
        const float bb = bp[h];
        mz0 = fmaf(p0, wz, mz0); mz1 = fmaf(p1, wz, mz1); mz2 = fmaf(p2, wz, mz2);
        cz  = fmaf(bb, wz, cz);
        mh0 = fmaf(p0, wh, mh0); mh1 = fmaf(p1, wh, mh1); mh2 = fmaf(p2, wh, mh2);
        ch  = fmaf(bb, wh, ch);
    }
    cz += bz[j];
    ch += bh[j];
    const float SZ = -1.4426950408889634f;   // -log2(e)
    const float SH = -2.8853900817779268f;   // -2*log2(e)
    float4* w4 = (float4*)(wsW + j * 8);
    w4[0] = make_float4(mz0 * SZ, mz1 * SZ, mz2 * SZ, cz * SZ);
    w4[1] = make_float4(mh0 * SH, mh1 * SH, mh2 * SH, ch * SH);
}

// ---------------------------------------------------------------------------
// Pass 1: per-(batch, segment) blocks of 256 threads (thread = channel).
// Compute segment-composite (A = prod a_t, B) with a = 1-z, b = z*htilde.
// Identities (1 rcp): r = 1/(d1*d2); a = e1*d2*r; z*ht = (2-d2)*r.
// ---------------------------------------------------------------------------
__global__ __launch_bounds__(256, 8) void pass1_seg(
        const float* __restrict__ x, const float* __restrict__ wsW,
        float* __restrict__ Aarr, float* __restrict__ Barr) {
    const int tid = threadIdx.x;
    const int b = blockIdx.x >> 4;         // NSEG = 16
    const int s = blockIdx.x & (NSEG - 1);

    const float4* wv = (const float4*)(wsW + tid * 8);
    const float4 wA = wv[0];
    const float4 wB = wv[1];

    __shared__ float4 xpad[SEGLEN];        // x padded to 4 floats per t
    float* xpf = (float*)xpad;
    const float* xs = x + ((size_t)b * NL + (size_t)s * SEGLEN) * 3;
    {
        float v = xs[tid];
        xpf[(tid / 3) * 4 + tid % 3] = v;
        if (tid < SEGLEN * 3 - 256) {
            const int w = 256 + tid;
            float v2 = xs[w];
            xpf[(w / 3) * 4 + w % 3] = v2;
        }
    }
    __syncthreads();

    float A = 1.f, Bacc = 0.f;
#pragma unroll 16
    for (int t = 0; t < SEGLEN; ++t) {
        const float4 xv = xpad[t];         // LDS broadcast
        const float e1 = fexp2(fmaf(xv.x, wA.x, fmaf(xv.y, wA.y, fmaf(xv.z, wA.z, wA.w))));
        const float e2 = fexp2(fmaf(xv.x, wB.x, fmaf(xv.y, wB.y, fmaf(xv.z, wB.z, wB.w))));
        const float d1 = 1.f + e1, d2 = 1.f + e2;
        const float r  = frcp(d1 * d2);
        const float a  = e1 * d2 * r;      // 1 - z
        const float zht = (2.f - d2) * r;  // z * tanh
        Bacc = fmaf(a, Bacc, zht);
        A *= a;
    }
    const size_t o = ((size_t)b * NSEG + s) * NH + tid;
    Aarr[o] = A;
    Barr[o] = Bacc;
}

// ---------------------------------------------------------------------------
// Pass 2: per-(b,chn) thread scans the NSEG segment composites to produce
// segment-START states. Written IN PLACE over Aarr (thread-private slots).
// ---------------------------------------------------------------------------
__global__ __launch_bounds__(256) void pass2_scan(
        float* __restrict__ AH, const float* __restrict__ Barr) {
    const int idx = blockIdx.x * 256 + threadIdx.x;   // b*NH + chn
    const int b = idx >> 8;
    const int chn = idx & 255;
    const size_t base = (size_t)b * NSEG * NH + chn;
    float Av[NSEG], Bv[NSEG];
#pragma unroll
    for (int s = 0; s < NSEG; ++s) {
        Av[s] = AH[base + (size_t)s * NH];            // independent loads, issued upfront
        Bv[s] = Barr[base + (size_t)s * NH];
    }
    float h = 0.f;
#pragma unroll
    for (int s = 0; s < NSEG; ++s) {
        AH[base + (size_t)s * NH] = h;                // h at segment START
        h = fmaf(Av[s], h, Bv[s]);
    }
}

// ---------------------------------------------------------------------------
// Pass 3: per-(batch, segment) blocks; recompute recurrence from h_start and
// emit preds. 256-channel reduction via LDS transpose (2-way conflicts = free)
// every RCHUNK timesteps; writes out directly (no partials/combine kernel).
// h update (1 rcp): h += (2 - (1+h)*d2) * rcp(d1*d2)   ==  (1-z)h + z*tanh.
// ---------------------------------------------------------------------------
__global__ __launch_bounds__(256, 8) void pass3_pred(
        const float* __restrict__ x, const float* __restrict__ wsW,
        const float* __restrict__ Wg, const float* __restrict__ bg,
        const float* __restrict__ Hs, float* __restrict__ out) {
    const int tid = threadIdx.x;
    const int b = blockIdx.x >> 4;
    const int s = blockIdx.x & (NSEG - 1);

    const float4* wv = (const float4*)(wsW + tid * 8);
    const float4 wA = wv[0];
    const float4 wB = wv[1];
    const float wg = Wg[tid];
    const float bgv = bg[0];

    __shared__ float4 xpad[SEGLEN];
    __shared__ float pbuf[RCHUNK][NH];                // 16 KB
    __shared__ float part2[2][RCHUNK][17];            // padded: 17 coprime 32
    float* xpf = (float*)xpad;
    const float* xs = x + ((size_t)b * NL + (size_t)s * SEGLEN) * 3;
    {
        float v = xs[tid];
        xpf[(tid / 3) * 4 + tid % 3] = v;
        if (tid < SEGLEN * 3 - 256) {
            const int w = 256 + tid;
            float v2 = xs[w];
            xpf[(w / 3) * 4 + w % 3] = v2;
        }
    }
    float h = Hs[((size_t)b * NSEG + s) * NH + tid];
    __syncthreads();

    for (int c = 0; c < SEGLEN / RCHUNK; ++c) {
        float p[RCHUNK];
#pragma unroll
        for (int u = 0; u < RCHUNK; ++u) {
            const float4 xv = xpad[c * RCHUNK + u];
            const float e1 = fexp2(fmaf(xv.x, wA.x, fmaf(xv.y, wA.y, fmaf(xv.z, wA.z, wA.w))));
            const float e2 = fexp2(fmaf(xv.x, wB.x, fmaf(xv.y, wB.y, fmaf(xv.z, wB.z, wB.w))));
            const float d1 = 1.f + e1, d2 = 1.f + e2;
            const float r  = frcp(d1 * d2);
            p[u] = h * wg;                             // pred uses h BEFORE update
            const float num = fmaf(-(1.f + h), d2, 2.f);
            h = fmaf(num, r, h);
        }
        // stage 1: all 256 channels dump p[] (addr stride 1 across lanes -> clean)
#pragma unroll
        for (int u = 0; u < RCHUNK; ++u) pbuf[u][tid] = p[u];
        __syncthreads();
        // stage 2: thread (t2, oct) sums 16 channels of timestep t2, rotated
        const int t2 = tid & 15, oct = tid >> 4;
        float acc = 0.f;
#pragma unroll
        for (int j = 0; j < 16; ++j)
            acc += pbuf[t2][oct * 16 + ((j + tid) & 15)];
        part2[c & 1][t2][oct] = acc;
        __syncthreads();
        // stage 3: final 16-way sum + bias, straight to out
        if (tid < RCHUNK) {
            float ss = bgv;
#pragma unroll
            for (int j = 0; j < 16; ++j) ss += part2[c & 1][tid][j];
            out[(size_t)b * NL + (size_t)s * SEGLEN + c * RCHUNK + tid] = ss;
        }
        // pbuf reuse is fenced by next iteration's first barrier; part2 is
        // double-buffered so stage-3 reads overlap next chunk's compute.
    }
}

// ---------------------------------------------------------------------------
// Fallback (ws too small): monolithic scan, 128 blocks x 256 thr.
// Weights are pre-scaled by fold_kernel (exp2 args direct).
// ---------------------------------------------------------------------------
__global__ __launch_bounds__(256) void scan_kernel_nows(
        const float* __restrict__ x, const float* __restrict__ wsW,
        const float* __restrict__ Wg, const float* __restrict__ bg,
        float* __restrict__ out) {
    const int tid  = threadIdx.x;
    const int lane = tid & 63;
    const int wid  = tid >> 6;
    const int b = blockIdx.x;
    const int chn = tid;

    const float4* wv = (const float4*)(wsW + chn * 8);
    const float4 wA = wv[0];
    const float4 wB = wv[1];
    const float  wg = Wg[chn];
    const float  bgv = bg[0];

    const float* xb = x + (size_t)b * (NL * 3);

    __shared__ float4 xbuf[2][CHUNK];
    __shared__ float  predbuf[2][4][CHUNK];
    float* xbf = (float*)xbuf;

    const int sw = tid;
    const int sidx = (sw / 3) * 4 + (sw % 3);

    if (tid < WORDS) xbf[sidx] = xb[sw];
    __syncthreads();

    float h = 0.f;
    for (int c = 0; c < NCHUNK; ++c) {
        const int cur = c & 1;
        float nv = 0.f;
        if (tid < WORDS && c + 1 < NCHUNK) nv = xb[(c + 1) * WORDS + sw];

        float p[CHUNK];
        const float4* xc = xbuf[cur];
#pragma unroll
        for (int t = 0; t < CHUNK; ++t) {
            const float4 xv = xc[t];
            const float e1 = fexp2(fmaf(xv.x, wA.x, fmaf(xv.y, wA.y, fmaf(xv.z, wA.z, wA.w))));
            const float e2 = fexp2(fmaf(xv.x, wB.x, fmaf(xv.y, wB.y, fmaf(xv.z, wB.z, wB.w))));
            const float d1 = 1.f + e1, d2 = 1.f + e2;
            const float r  = frcp(d1 * d2);
            p[t] = h * wg;
            const float num = fmaf(-(1.f + h), d2, 2.f);
            h = fmaf(num, r, h);
        }
#pragma unroll
        for (int t = 0; t < CHUNK; ++t) {
            float v = p[t];
            v += __shfl_xor(v, 1, 64);
            v += __shfl_xor(v, 2, 64);
            v += __shfl_xor(v, 4, 64);
            v += __shfl_xor(v, 8, 64);
            v += __shfl_xor(v, 16, 64);
            v += __shfl_xor(v, 32, 64);
            p[t] = v;
        }
        if (lane == 0) {
            float4* dpr = (float4*)&predbuf[cur][wid][0];
#pragma unroll
            for (int j2 = 0; j2 < CHUNK / 4; ++j2)
                dpr[j2] = make_float4(p[4*j2], p[4*j2+1], p[4*j2+2], p[4*j2+3]);
        }
        if (tid < WORDS && c + 1 < NCHUNK) xbf[(cur ^ 1) * CHUNK * 4 + sidx] = nv;
        __syncthreads();
        if (tid < CHUNK) {
            const float ssum = predbuf[cur][0][tid] + predbuf[cur][1][tid]
                             + predbuf[cur][2][tid] + predbuf[cur][3][tid];
            out[(size_t)b * NL + c * CHUNK + tid] = ssum + bgv;
        }
    }
}

extern "C" void kernel_launch(void* const* d_in, const int* in_sizes, int n_in,
                              void* d_out, int out_size, void* d_ws, size_t ws_size,
                              hipStream_t stream) {
    const float* x  = (const float*)d_in[0];
    const float* Wp = (const float*)d_in[1];
    const float* bp = (const float*)d_in[2];
    const float* Wz = (const float*)d_in[3];
    const float* bz = (const float*)d_in[4];
    const float* Wh = (const float*)d_in[5];
    const float* bh = (const float*)d_in[6];
    const float* Wg = (const float*)d_in[7];
    const float* bg = (const float*)d_in[8];
    float* out = (float*)d_out;

    float* wsW = (float*)d_ws;                       // 8 KB folded weights

    fold_kernel<<<4, 64, 0, stream>>>(Wp, bp, Wz, bz, Wh, bh, wsW);

    // need = 8KB weights + A(2MB) + B(2MB); Hs is written in place over A.
    const size_t need = (size_t)(8 * NH) * sizeof(float)
                      + (size_t)2 * NB * NSEG * NH * sizeof(float);
    if (ws_size >= need) {
        float* Aarr = wsW + 8 * NH;                  // later becomes Hs
        float* Barr = Aarr + (size_t)NB * NSEG * NH;
        pass1_seg<<<NB * NSEG, 256, 0, stream>>>(x, wsW, Aarr, Barr);
        pass2_scan<<<(NB * NH) / 256, 256, 0, stream>>>(Aarr, Barr);
        pass3_pred<<<NB * NSEG, 256, 0, stream>>>(x, wsW, Wg, bg, Aarr, out);
    } else {
        scan_kernel_nows<<<NB, 256, 0, stream>>>(x, wsW, Wg, bg, out);
    }
}

// Round 3
// 91.991 us; speedup vs baseline: 2.5239x; 1.0543x over previous
//
#include <hip/hip_runtime.h>

#define NB 128
#define NL 2048
#define NH 256
#define NSEG 16
#define SEGLEN (NL / NSEG)   // 128
#define RCHUNK 16            // pred-reduce chunk inside pass3
#define XPITCH (SEGLEN + 8)  // LDS plane pitch (pad breaks staging conflicts)
#define CHUNK 32             // fallback kernel chunking
#define NCHUNK (NL / CHUNK)
#define WORDS (CHUNK * 3)

typedef float f32x2 __attribute__((ext_vector_type(2)));

__device__ __forceinline__ float fexp2(float v) { return __builtin_amdgcn_exp2f(v); }
__device__ __forceinline__ float frcp(float v)  { return __builtin_amdgcn_rcpf(v); }

__device__ __forceinline__ f32x2 pkfma(f32x2 a, f32x2 b, f32x2 c) {
#if __has_builtin(__builtin_elementwise_fma)
    return __builtin_elementwise_fma(a, b, c);   // -> v_pk_fma_f32
#else
    f32x2 r; r.x = fmaf(a.x, b.x, c.x); r.y = fmaf(a.y, b.y, c.y); return r;
#endif
}
__device__ __forceinline__ f32x2 splat2(float v) { f32x2 r; r.x = v; r.y = v; return r; }

// ---------------------------------------------------------------------------
// Fold K=3 projection through Wz/Wh, pre-scaled by exp2 constants:
//   gate arg s1 = dot(x,Mz)+cz scaled by -log2e  -> z = 1/(1+2^s1)
//   cand arg s2 = dot(x,Mh)+ch scaled by -2log2e -> tanh = 2/(1+2^s2)-1
// ---------------------------------------------------------------------------
__global__ void fold_kernel(const float* __restrict__ Wp, const float* __restrict__ bp,
                            const float* __restrict__ Wz, const float* __restrict__ bz,
                            const float* __restrict__ Wh, const float* __restrict__ bh,
                            float* __restrict__ wsW) {
    const int j = blockIdx.x * 64 + threadIdx.x;   // grid <<<4,64>>>
    float mz0 = 0.f, mz1 = 0.f, mz2 = 0.f, cz = 0.f;
    float mh0 = 0.f, mh1 = 0.f, mh2 = 0.f, ch = 0.f;
#pragma unroll 16
    for (int h = 0; h < NH; ++h) {
        const float wz = Wz[h * NH + j];
        const float wh = Wh[h * NH + j];
        const float p0 = Wp[h];            // uniform -> s_load
        const float p1 = Wp[NH + h];
        const float p2 = Wp[2 * NH + h];
        const float bb = bp[h];
        mz0 = fmaf(p0, wz, mz0); mz1 = fmaf(p1, wz, mz1); mz2 = fmaf(p2, wz, mz2);
        cz  = fmaf(bb, wz, cz);
        mh0 = fmaf(p0, wh, mh0); mh1 = fmaf(p1, wh, mh1); mh2 = fmaf(p2, wh, mh2);
        ch  = fmaf(bb, wh, ch);
    }
    cz += bz[j];
    ch += bh[j];
    const float SZ = -1.4426950408889634f;   // -log2(e)
    const float SH = -2.8853900817779268f;   // -2*log2(e)
    float4* w4 = (float4*)(wsW + j * 8);
    w4[0] = make_float4(mz0 * SZ, mz1 * SZ, mz2 * SZ, cz * SZ);
    w4[1] = make_float4(mh0 * SH, mh1 * SH, mh2 * SH, ch * SH);
}

// Stage x segment into 3 transposed LDS planes: xpl[c][t] = x[t*3+c].
__device__ __forceinline__ void stage_x(const float* __restrict__ xs,
                                        float (*xpl)[XPITCH], int tid) {
    {
        const int w = tid;
        const float v = xs[w];
        xpl[w % 3][w / 3] = v;
    }
    const int w2 = tid + 256;
    if (w2 < SEGLEN * 3) {
        const float v2 = xs[w2];
        xpl[w2 % 3][w2 / 3] = v2;
    }
}

// ---------------------------------------------------------------------------
// Pass 1: per-(batch, segment) blocks of 256 threads (thread = channel).
// Segment composite (A, B): h_end = A*h_start + B. Packed 2-timestep math.
// ---------------------------------------------------------------------------
__global__ __launch_bounds__(256, 8) void pass1_seg(
        const float* __restrict__ x, const float* __restrict__ wsW,
        float* __restrict__ Aarr, float* __restrict__ Barr) {
    const int tid = threadIdx.x;
    const int b = blockIdx.x >> 4;         // NSEG = 16
    const int s = blockIdx.x & (NSEG - 1);

    const float4* wv = (const float4*)(wsW + tid * 8);
    const float4 wA = wv[0];
    const float4 wB = wv[1];
    const f32x2 wax = splat2(wA.x), way = splat2(wA.y), waz = splat2(wA.z), waw = splat2(wA.w);
    const f32x2 wbx = splat2(wB.x), wby = splat2(wB.y), wbz = splat2(wB.z), wbw = splat2(wB.w);

    __shared__ float xpl[3][XPITCH];
    const float* xs = x + ((size_t)b * NL + (size_t)s * SEGLEN) * 3;
    stage_x(xs, xpl, tid);
    __syncthreads();

    float A = 1.f, Bacc = 0.f;
#pragma unroll 8
    for (int t = 0; t < SEGLEN; t += 2) {
        const f32x2 xx = *(const f32x2*)&xpl[0][t];   // ds_read_b64 broadcast
        const f32x2 xy = *(const f32x2*)&xpl[1][t];
        const f32x2 xz = *(const f32x2*)&xpl[2][t];
        const f32x2 s1 = pkfma(xx, wax, pkfma(xy, way, pkfma(xz, waz, waw)));
        const f32x2 s2 = pkfma(xx, wbx, pkfma(xy, wby, pkfma(xz, wbz, wbw)));
        f32x2 e1, e2, rr;
        e1.x = fexp2(s1.x); e1.y = fexp2(s1.y);
        e2.x = fexp2(s2.x); e2.y = fexp2(s2.y);
        const f32x2 d2 = e2 + 1.f;
        const f32x2 e1d2 = e1 * d2;
        const f32x2 dd = e1d2 + d2;        // (1+e1)(1+e2) without forming d1
        rr.x = frcp(dd.x); rr.y = frcp(dd.y);
        const f32x2 av = e1d2 * rr;        // a = 1-z
        const f32x2 bv = (1.f - e2) * rr;  // b = z*tanh
        Bacc = fmaf(av.x, Bacc, bv.x);
        Bacc = fmaf(av.y, Bacc, bv.y);
        A *= av.x * av.y;
    }
    const size_t o = ((size_t)b * NSEG + s) * NH + tid;
    Aarr[o] = A;
    Barr[o] = Bacc;
}

// ---------------------------------------------------------------------------
// Pass 2: per-(b,chn) thread scans NSEG composites -> segment-START states,
// written in place over Aarr.
// ---------------------------------------------------------------------------
__global__ __launch_bounds__(256) void pass2_scan(
        float* __restrict__ AH, const float* __restrict__ Barr) {
    const int idx = blockIdx.x * 256 + threadIdx.x;
    const int b = idx >> 8;
    const int chn = idx & 255;
    const size_t base = (size_t)b * NSEG * NH + chn;
    float Av[NSEG], Bv[NSEG];
#pragma unroll
    for (int s = 0; s < NSEG; ++s) {
        Av[s] = AH[base + (size_t)s * NH];
        Bv[s] = Barr[base + (size_t)s * NH];
    }
    float h = 0.f;
#pragma unroll
    for (int s = 0; s < NSEG; ++s) {
        AH[base + (size_t)s * NH] = h;
        h = fmaf(Av[s], h, Bv[s]);
    }
}

// ---------------------------------------------------------------------------
// Pass 3: recompute within-segment states from h_start, emit preds.
// Packed gate math -> per-t serial chain is a single fma (h = a*h + b).
// 256-channel pred reduction via rotated LDS transpose every RCHUNK steps.
// ---------------------------------------------------------------------------
__global__ __launch_bounds__(256, 8) void pass3_pred(
        const float* __restrict__ x, const float* __restrict__ wsW,
        const float* __restrict__ Wg, const float* __restrict__ bg,
        const float* __restrict__ Hs, float* __restrict__ out) {
    const int tid = threadIdx.x;
    const int b = blockIdx.x >> 4;
    const int s = blockIdx.x & (NSEG - 1);

    const float4* wv = (const float4*)(wsW + tid * 8);
    const float4 wA = wv[0];
    const float4 wB = wv[1];
    const f32x2 wax = splat2(wA.x), way = splat2(wA.y), waz = splat2(wA.z), waw = splat2(wA.w);
    const f32x2 wbx = splat2(wB.x), wby = splat2(wB.y), wbz = splat2(wB.z), wbw = splat2(wB.w);
    const float wg = Wg[tid];
    const float bgv = bg[0];

    __shared__ float xpl[3][XPITCH];
    __shared__ float pbuf[RCHUNK][NH];                // 16 KB
    __shared__ float part2[2][RCHUNK][17];
    const float* xs = x + ((size_t)b * NL + (size_t)s * SEGLEN) * 3;
    stage_x(xs, xpl, tid);
    float h = Hs[((size_t)b * NSEG + s) * NH + tid];
    __syncthreads();

    for (int c = 0; c < SEGLEN / RCHUNK; ++c) {
        float p[RCHUNK];
#pragma unroll
        for (int u = 0; u < RCHUNK; u += 2) {
            const int t = c * RCHUNK + u;
            const f32x2 xx = *(const f32x2*)&xpl[0][t];
            const f32x2 xy = *(const f32x2*)&xpl[1][t];
            const f32x2 xz = *(const f32x2*)&xpl[2][t];
            const f32x2 s1 = pkfma(xx, wax, pkfma(xy, way, pkfma(xz, waz, waw)));
            const f32x2 s2 = pkfma(xx, wbx, pkfma(xy, wby, pkfma(xz, wbz, wbw)));
            f32x2 e1, e2, rr;
            e1.x = fexp2(s1.x); e1.y = fexp2(s1.y);
            e2.x = fexp2(s2.x); e2.y = fexp2(s2.y);
            const f32x2 d2 = e2 + 1.f;
            const f32x2 e1d2 = e1 * d2;
            const f32x2 dd = e1d2 + d2;
            rr.x = frcp(dd.x); rr.y = frcp(dd.y);
            const f32x2 av = e1d2 * rr;
            const f32x2 bv = (1.f - e2) * rr;
            p[u] = h * wg;                 // pred uses h BEFORE update
            h = fmaf(av.x, h, bv.x);
            p[u + 1] = h * wg;
            h = fmaf(av.y, h, bv.y);
        }
#pragma unroll
        for (int u = 0; u < RCHUNK; ++u) pbuf[u][tid] = p[u];
        __syncthreads();
        const int t2 = tid & 15, oct = tid >> 4;
        float acc = 0.f;
#pragma unroll
        for (int j = 0; j < 16; ++j)
            acc += pbuf[t2][oct * 16 + ((j + tid) & 15)];   // rotation: 2-way max
        part2[c & 1][t2][oct] = acc;
        __syncthreads();
        if (tid < RCHUNK) {
            float ss = bgv;
#pragma unroll
            for (int j = 0; j < 16; ++j) ss += part2[c & 1][tid][j];
            out[(size_t)b * NL + (size_t)s * SEGLEN + c * RCHUNK + tid] = ss;
        }
    }
}

// ---------------------------------------------------------------------------
// Fallback (ws too small): monolithic scan, unchanged structure.
// ---------------------------------------------------------------------------
__global__ __launch_bounds__(256) void scan_kernel_nows(
        const float* __restrict__ x, const float* __restrict__ wsW,
        const float* __restrict__ Wg, const float* __restrict__ bg,
        float* __restrict__ out) {
    const int tid  = threadIdx.x;
    const int lane = tid & 63;
    const int wid  = tid >> 6;
    const int b = blockIdx.x;

    const float4* wv = (const float4*)(wsW + tid * 8);
    const float4 wA = wv[0];
    const float4 wB = wv[1];
    const float  wg = Wg[tid];
    const float  bgv = bg[0];

    const float* xb = x + (size_t)b * (NL * 3);

    __shared__ float4 xbuf[2][CHUNK];
    __shared__ float  predbuf[2][4][CHUNK];
    float* xbf = (float*)xbuf;

    const int sw = tid;
    const int sidx = (sw / 3) * 4 + (sw % 3);

    if (tid < WORDS) xbf[sidx] = xb[sw];
    __syncthreads();

    float h = 0.f;
    for (int c = 0; c < NCHUNK; ++c) {
        const int cur = c & 1;
        float nv = 0.f;
        if (tid < WORDS && c + 1 < NCHUNK) nv = xb[(c + 1) * WORDS + sw];

        float p[CHUNK];
        const float4* xc = xbuf[cur];
#pragma unroll
        for (int t = 0; t < CHUNK; ++t) {
            const float4 xv = xc[t];
            const float e1 = fexp2(fmaf(xv.x, wA.x, fmaf(xv.y, wA.y, fmaf(xv.z, wA.z, wA.w))));
            const float e2 = fexp2(fmaf(xv.x, wB.x, fmaf(xv.y, wB.y, fmaf(xv.z, wB.z, wB.w))));
            const float d2 = 1.f + e2;
            const float e1d2 = e1 * d2;
            const float r  = frcp(e1d2 + d2);
            p[t] = h * wg;
            h = fmaf(e1d2 * r, h, (1.f - e2) * r);
        }
#pragma unroll
        for (int t = 0; t < CHUNK; ++t) {
            float v = p[t];
            v += __shfl_xor(v, 1, 64);
            v += __shfl_xor(v, 2, 64);
            v += __shfl_xor(v, 4, 64);
            v += __shfl_xor(v, 8, 64);
            v += __shfl_xor(v, 16, 64);
            v += __shfl_xor(v, 32, 64);
            p[t] = v;
        }
        if (lane == 0) {
            float4* dpr = (float4*)&predbuf[cur][wid][0];
#pragma unroll
            for (int j2 = 0; j2 < CHUNK / 4; ++j2)
                dpr[j2] = make_float4(p[4*j2], p[4*j2+1], p[4*j2+2], p[4*j2+3]);
        }
        if (tid < WORDS && c + 1 < NCHUNK) xbf[(cur ^ 1) * CHUNK * 4 + sidx] = nv;
        __syncthreads();
        if (tid < CHUNK) {
            const float ssum = predbuf[cur][0][tid] + predbuf[cur][1][tid]
                             + predbuf[cur][2][tid] + predbuf[cur][3][tid];
            out[(size_t)b * NL + c * CHUNK + tid] = ssum + bgv;
        }
    }
}

extern "C" void kernel_launch(void* const* d_in, const int* in_sizes, int n_in,
                              void* d_out, int out_size, void* d_ws, size_t ws_size,
                              hipStream_t stream) {
    const float* x  = (const float*)d_in[0];
    const float* Wp = (const float*)d_in[1];
    const float* bp = (const float*)d_in[2];
    const float* Wz = (const float*)d_in[3];
    const float* bz = (const float*)d_in[4];
    const float* Wh = (const float*)d_in[5];
    const float* bh = (const float*)d_in[6];
    const float* Wg = (const float*)d_in[7];
    const float* bg = (const float*)d_in[8];
    float* out = (float*)d_out;

    float* wsW = (float*)d_ws;                       // 8 KB folded weights

    fold_kernel<<<4, 64, 0, stream>>>(Wp, bp, Wz, bz, Wh, bh, wsW);

    const size_t need = (size_t)(8 * NH) * sizeof(float)
                      + (size_t)2 * NB * NSEG * NH * sizeof(float);
    if (ws_size >= need) {
        float* Aarr = wsW + 8 * NH;                  // later becomes Hs
        float* Barr = Aarr + (size_t)NB * NSEG * NH;
        pass1_seg<<<NB * NSEG, 256, 0, stream>>>(x, wsW, Aarr, Barr);
        pass2_scan<<<(NB * NH) / 256, 256, 0, stream>>>(Aarr, Barr);
        pass3_pred<<<NB * NSEG, 256, 0, stream>>>(x, wsW, Wg, bg, Aarr, out);
    } else {
        scan_kernel_nows<<<NB, 256, 0, stream>>>(x, wsW, Wg, bg, out);
    }
}